// Round 2
// baseline (231.466 us; speedup 1.0000x reference)
//
#include <hip/hip_runtime.h>
#include <hip/hip_bf16.h>
#include <math.h>

#define DIM 256

typedef __bf16 bf16x8 __attribute__((ext_vector_type(8)));
typedef float f32x4 __attribute__((ext_vector_type(4)));

__constant__ const float kTempInvLog2e = 20.0f * 1.4426950408889634f; // (1/temp)*log2(e)
#define LN2 0.6931471805599453f
#define EPS_NORM 1e-8f

// round-to-nearest-even f32 -> bf16 bits
static __device__ inline unsigned short f2bf(float f) {
    unsigned u = __builtin_bit_cast(unsigned, f);
    unsigned r = (u + 0x7fffu + ((u >> 16) & 1u)) >> 16;
    return (unsigned short)r;
}

// Kernel 1: per-row L2 normalize of BOTH A and B row r, emit bf16, and compute
// diag[r] = (a_r . b_r)/(|a||b|) * (1/temp) * log2(e)   (log2-domain logit)
// One wave per row. A rows carry the temp*log2e scale; B rows are unit.
__global__ __launch_bounds__(64) void normalize_kernel(
    const float* __restrict__ A, const float* __restrict__ B,
    unsigned short* __restrict__ Abf, unsigned short* __restrict__ Bbf,
    float* __restrict__ diag, int n)
{
    const int r = blockIdx.x;
    const int lane = threadIdx.x;
    float4 a = ((const float4*)(A + (size_t)r * DIM))[lane];
    float4 b = ((const float4*)(B + (size_t)r * DIM))[lane];

    float ssa = a.x * a.x + a.y * a.y + a.z * a.z + a.w * a.w;
    float ssb = b.x * b.x + b.y * b.y + b.z * b.z + b.w * b.w;
    float dd  = a.x * b.x + a.y * b.y + a.z * b.z + a.w * b.w;
#pragma unroll
    for (int m = 1; m < 64; m <<= 1) {
        ssa += __shfl_xor(ssa, m, 64);
        ssb += __shfl_xor(ssb, m, 64);
        dd  += __shfl_xor(dd, m, 64);
    }
    float na = fmaxf(sqrtf(ssa), EPS_NORM);
    float nb = fmaxf(sqrtf(ssb), EPS_NORM);
    float sa = kTempInvLog2e / na;
    float sb = 1.0f / nb;

    ushort4 oa, ob;
    oa.x = f2bf(a.x * sa); oa.y = f2bf(a.y * sa); oa.z = f2bf(a.z * sa); oa.w = f2bf(a.w * sa);
    ob.x = f2bf(b.x * sb); ob.y = f2bf(b.y * sb); ob.z = f2bf(b.z * sb); ob.w = f2bf(b.w * sb);
    ((ushort4*)(Abf + (size_t)r * DIM))[lane] = oa;
    ((ushort4*)(Bbf + (size_t)r * DIM))[lane] = ob;

    if (lane == 0) diag[r] = dd / (na * nb) * kTempInvLog2e;
}

// Kernel 2: fused GEMM (bf16 MFMA 16x16x32) + exp2 + per-row partial sums.
// Block = 256 thr (4 waves), covers 64 rows x (n/4) cols. A fragments persist
// in registers (128 VGPRs); B tiles double-buffered in registers (prefetch next
// 64-col tile during MFMA+epilogue). No diag logic in the loop.
// partial layout is ROW-major: partial[row*16 + (split*4 + w)] for coalesced
// reads in the reduction.
__global__ __launch_bounds__(256, 2) void gemm_lse_kernel(
    const unsigned short* __restrict__ Abf, const unsigned short* __restrict__ Bbf,
    float* __restrict__ partial, int n)
{
    const int lane = threadIdx.x & 63;
    const int w = threadIdx.x >> 6;
    const int c = lane & 15;   // M index (A), N index (B), col index (C/D)
    const int q = lane >> 4;   // K-chunk index (A,B); row-quad (C/D)
    const int rowbase = blockIdx.x * 64;
    const int ncols = n >> 2;                 // cols per split
    const int colstart = blockIdx.y * ncols;

    // persistent A fragments: 4 Mtiles x 8 Ksteps x 16B = 128 VGPRs
    bf16x8 afrag[4][8];
#pragma unroll
    for (int t = 0; t < 4; ++t) {
        const unsigned short* ap = Abf + (size_t)(rowbase + t * 16 + c) * DIM + q * 8;
#pragma unroll
        for (int k = 0; k < 8; ++k)
            afrag[t][k] = *(const bf16x8*)(ap + k * 32);
    }

    float sums[16];
#pragma unroll
    for (int i = 0; i < 16; ++i) sums[i] = 0.0f;

    const unsigned short* bp0 = Bbf + (size_t)(colstart + w * 16 + c) * DIM + q * 8;
    const int niter = ncols / 64;

    // prime buffer 0
    bf16x8 bbuf[2][8];
#pragma unroll
    for (int k = 0; k < 8; ++k)
        bbuf[0][k] = *(const bf16x8*)(bp0 + k * 32);

#pragma unroll 2
    for (int it = 0; it < niter; ++it) {
        const int cur = it & 1;
        // prefetch next tile (last iteration reads one tile past the split;
        // that address stays inside the workspace and the data is unused)
        const unsigned short* bpn = bp0 + (size_t)(it + 1) * 64 * DIM;
#pragma unroll
        for (int k = 0; k < 8; ++k)
            bbuf[cur ^ 1][k] = *(const bf16x8*)(bpn + k * 32);

        f32x4 acc[4];
#pragma unroll
        for (int t = 0; t < 4; ++t) acc[t] = (f32x4){0.f, 0.f, 0.f, 0.f};

#pragma unroll
        for (int k = 0; k < 8; ++k) {
#pragma unroll
            for (int t = 0; t < 4; ++t)
                acc[t] = __builtin_amdgcn_mfma_f32_16x16x32_bf16(
                    afrag[t][k], bbuf[cur][k], acc[t], 0, 0, 0);
        }

#pragma unroll
        for (int t = 0; t < 4; ++t) {
#pragma unroll
            for (int r = 0; r < 4; ++r)
                sums[t * 4 + r] += __builtin_amdgcn_exp2f(acc[t][r]);
        }
    }

    // reduce each row sum across the 16 lanes of its q-group (cols mod 16)
#pragma unroll
    for (int i = 0; i < 16; ++i) {
        float s = sums[i];
        s += __shfl_xor(s, 1, 64);
        s += __shfl_xor(s, 2, 64);
        s += __shfl_xor(s, 4, 64);
        s += __shfl_xor(s, 8, 64);
        sums[i] = s;
    }
    if (c == 0) {
        const int p = blockIdx.y * 4 + w;
#pragma unroll
        for (int t = 0; t < 4; ++t)
#pragma unroll
            for (int r = 0; r < 4; ++r)
                partial[(size_t)(rowbase + t * 16 + q * 4 + r) * 16 + p] = sums[t * 4 + r];
    }
}

// Kernel 3a: per-row lse - diag, block-reduced. One row per thread, 32 blocks.
__global__ __launch_bounds__(256) void row_lse_kernel(
    const float* __restrict__ partial, const float* __restrict__ diag,
    float* __restrict__ bsum, int n)
{
    __shared__ float red[256];
    const int row = blockIdx.x * 256 + threadIdx.x;
    float local = 0.0f;
    if (row < n) {
        const float4* p = (const float4*)(partial + (size_t)row * 16);
        float4 p0 = p[0], p1 = p[1], p2 = p[2], p3 = p[3];
        float s = (p0.x + p0.y + p0.z + p0.w) + (p1.x + p1.y + p1.z + p1.w)
                + (p2.x + p2.y + p2.z + p2.w) + (p3.x + p3.y + p3.z + p3.w);
        local = log2f(s) - diag[row];
    }
    red[threadIdx.x] = local;
    __syncthreads();
    for (int off = 128; off > 0; off >>= 1) {
        if (threadIdx.x < off) red[threadIdx.x] += red[threadIdx.x + off];
        __syncthreads();
    }
    if (threadIdx.x == 0) bsum[blockIdx.x] = red[0];
}

// Kernel 3b: final reduce of block sums -> loss.
__global__ __launch_bounds__(64) void final_kernel(
    const float* __restrict__ bsum, float* __restrict__ out, int nblocks, int n)
{
    float v = (threadIdx.x < nblocks) ? bsum[threadIdx.x] : 0.0f;
#pragma unroll
    for (int m = 1; m < 64; m <<= 1) v += __shfl_xor(v, m, 64);
    if (threadIdx.x == 0) out[0] = v * (LN2 / (float)n);
}

extern "C" void kernel_launch(void* const* d_in, const int* in_sizes, int n_in,
                              void* d_out, int out_size, void* d_ws, size_t ws_size,
                              hipStream_t stream) {
    const int n = in_sizes[0] / DIM;  // 8192
    const float* A = (const float*)d_in[0];
    const float* B = (const float*)d_in[1];
    float* out = (float*)d_out;

    // workspace layout
    unsigned short* Abf = (unsigned short*)d_ws;                 // n*DIM bf16
    unsigned short* Bbf = Abf + (size_t)n * DIM;                 // n*DIM bf16
    float* partial = (float*)(Bbf + (size_t)n * DIM);            // n*16 f32 (row-major)
    float* diag = partial + (size_t)n * 16;                      // n f32
    float* bsum = diag + n;                                      // 32 f32

    normalize_kernel<<<n, 64, 0, stream>>>(A, B, Abf, Bbf, diag, n);

    dim3 grid(n / 64, 4);
    gemm_lse_kernel<<<grid, 256, 0, stream>>>(Abf, Bbf, partial, n);

    const int nred = (n + 255) / 256;  // 32
    row_lse_kernel<<<nred, 256, 0, stream>>>(partial, diag, bsum, n);
    final_kernel<<<1, 64, 0, stream>>>(bsum, out, nred, n);
}

// Round 3
// 137.289 us; speedup vs baseline: 1.6860x; 1.6860x over previous
//
#include <hip/hip_runtime.h>
#include <hip/hip_bf16.h>
#include <math.h>

#define DIM 256

typedef __bf16 bf16x8 __attribute__((ext_vector_type(8)));
typedef float f32x4 __attribute__((ext_vector_type(4)));

__constant__ const float kTempInvLog2e = 20.0f * 1.4426950408889634f; // (1/temp)*log2(e)
#define LN2 0.6931471805599453f
#define EPS_NORM 1e-8f

// round-to-nearest-even f32 -> bf16 bits
static __device__ inline unsigned short f2bf(float f) {
    unsigned u = __builtin_bit_cast(unsigned, f);
    unsigned r = (u + 0x7fffu + ((u >> 16) & 1u)) >> 16;
    return (unsigned short)r;
}

// Kernel 1: per-row L2 normalize of BOTH A and B, emit bf16, plus
// diag[r] = cos(a_r,b_r)*(1/temp)*log2(e). 4 rows per 256-thr block (1 wave/row).
__global__ __launch_bounds__(256) void normalize_kernel(
    const float* __restrict__ A, const float* __restrict__ B,
    unsigned short* __restrict__ Abf, unsigned short* __restrict__ Bbf,
    float* __restrict__ diag, int n)
{
    const int r = blockIdx.x * 4 + (threadIdx.x >> 6);
    const int lane = threadIdx.x & 63;
    float4 a = ((const float4*)(A + (size_t)r * DIM))[lane];
    float4 b = ((const float4*)(B + (size_t)r * DIM))[lane];

    float ssa = a.x * a.x + a.y * a.y + a.z * a.z + a.w * a.w;
    float ssb = b.x * b.x + b.y * b.y + b.z * b.z + b.w * b.w;
    float dd  = a.x * b.x + a.y * b.y + a.z * b.z + a.w * b.w;
#pragma unroll
    for (int m = 1; m < 64; m <<= 1) {
        ssa += __shfl_xor(ssa, m, 64);
        ssb += __shfl_xor(ssb, m, 64);
        dd  += __shfl_xor(dd, m, 64);
    }
    float na = fmaxf(sqrtf(ssa), EPS_NORM);
    float nb = fmaxf(sqrtf(ssb), EPS_NORM);
    float sa = kTempInvLog2e / na;
    float sb = 1.0f / nb;

    ushort4 oa, ob;
    oa.x = f2bf(a.x * sa); oa.y = f2bf(a.y * sa); oa.z = f2bf(a.z * sa); oa.w = f2bf(a.w * sa);
    ob.x = f2bf(b.x * sb); ob.y = f2bf(b.y * sb); ob.z = f2bf(b.z * sb); ob.w = f2bf(b.w * sb);
    ((ushort4*)(Abf + (size_t)r * DIM))[lane] = oa;
    ((ushort4*)(Bbf + (size_t)r * DIM))[lane] = ob;

    if (lane == 0) diag[r] = dd / (na * nb) * kTempInvLog2e;
}

#define LOAD_B(buf, ptr)                                   \
    _Pragma("unroll")                                      \
    for (int k = 0; k < 8; ++k)                            \
        buf[k] = *(const bf16x8*)((ptr) + k * 32);

#define COMPUTE_TILE(buf)                                  \
    {                                                      \
        f32x4 acc[4];                                      \
        _Pragma("unroll")                                  \
        for (int t = 0; t < 4; ++t) acc[t] = (f32x4){0.f, 0.f, 0.f, 0.f}; \
        _Pragma("unroll")                                  \
        for (int k = 0; k < 8; ++k) {                      \
            _Pragma("unroll")                              \
            for (int t = 0; t < 4; ++t)                    \
                acc[t] = __builtin_amdgcn_mfma_f32_16x16x32_bf16( \
                    afrag[t][k], buf[k], acc[t], 0, 0, 0); \
        }                                                  \
        _Pragma("unroll")                                  \
        for (int t = 0; t < 4; ++t) {                      \
            _Pragma("unroll")                              \
            for (int r = 0; r < 4; ++r)                    \
                sums[t * 4 + r] += __builtin_amdgcn_exp2f(acc[t][r]); \
        }                                                  \
    }

// Kernel 2: fused GEMM (bf16 MFMA 16x16x32) + exp2 + per-row partial sums.
// Block = 256 thr (4 waves), covers 64 rows x (n/4) cols. A fragments pinned
// in registers via empty-asm (128 VGPRs); B register double-buffered with
// compile-time indices (two named buffers, step-2 loop).
__global__ __launch_bounds__(256, 2) void gemm_lse_kernel(
    const unsigned short* __restrict__ Abf, const unsigned short* __restrict__ Bbf,
    float* __restrict__ partial, int n)
{
    const int lane = threadIdx.x & 63;
    const int w = threadIdx.x >> 6;
    const int c = lane & 15;   // M index (A), N index (B), col index (C/D)
    const int q = lane >> 4;   // K-chunk index (A,B); row-quad (C/D)
    const int rowbase = blockIdx.x * 64;
    const int ncols = n >> 2;                 // cols per split
    const int colstart = blockIdx.y * ncols;

    // persistent A fragments: 4 Mtiles x 8 Ksteps x 16B = 128 VGPRs
    bf16x8 afrag[4][8];
#pragma unroll
    for (int t = 0; t < 4; ++t) {
        const unsigned short* ap = Abf + (size_t)(rowbase + t * 16 + c) * DIM + q * 8;
#pragma unroll
        for (int k = 0; k < 8; ++k)
            afrag[t][k] = *(const bf16x8*)(ap + k * 32);
    }
    // pin afrag in VGPRs: the asm reads+writes each fragment, so the loads
    // above cannot be rematerialized/sunk into the loop below.
#pragma unroll
    for (int t = 0; t < 4; ++t)
#pragma unroll
        for (int k = 0; k < 8; ++k)
            asm volatile("" : "+v"(*(f32x4*)&afrag[t][k]));

    float sums[16];
#pragma unroll
    for (int i = 0; i < 16; ++i) sums[i] = 0.0f;

    const unsigned short* bp0 = Bbf + (size_t)(colstart + w * 16 + c) * DIM + q * 8;
    const int niter = ncols / 64;   // 32 for n=8192 (even)

    // explicit register double-buffer, compile-time indices only
    bf16x8 b0[8], b1[8];
    LOAD_B(b0, bp0);

    for (int it = 0; it < niter; it += 2) {
        const unsigned short* bpn1 = bp0 + (size_t)(it + 1) * 64 * DIM;
        LOAD_B(b1, bpn1);          // prefetch tile it+1
        COMPUTE_TILE(b0);          // compute tile it

        const unsigned short* bpn2 = bp0 + (size_t)(it + 2) * 64 * DIM;
        LOAD_B(b0, bpn2);          // prefetch tile it+2 (tail read stays in ws)
        COMPUTE_TILE(b1);          // compute tile it+1
    }

    // reduce each row sum across the 16 lanes of its q-group (cols mod 16)
#pragma unroll
    for (int i = 0; i < 16; ++i) {
        float s = sums[i];
        s += __shfl_xor(s, 1, 64);
        s += __shfl_xor(s, 2, 64);
        s += __shfl_xor(s, 4, 64);
        s += __shfl_xor(s, 8, 64);
        sums[i] = s;
    }
    if (c == 0) {
        const int p = blockIdx.y * 4 + w;
#pragma unroll
        for (int t = 0; t < 4; ++t)
#pragma unroll
            for (int r = 0; r < 4; ++r)
                partial[(size_t)(rowbase + t * 16 + q * 4 + r) * 16 + p] = sums[t * 4 + r];
    }
}

// Kernel 3a: per-row lse - diag, block-reduced. One row per thread, 32 blocks.
__global__ __launch_bounds__(256) void row_lse_kernel(
    const float* __restrict__ partial, const float* __restrict__ diag,
    float* __restrict__ bsum, int n)
{
    __shared__ float red[256];
    const int row = blockIdx.x * 256 + threadIdx.x;
    float local = 0.0f;
    if (row < n) {
        const float4* p = (const float4*)(partial + (size_t)row * 16);
        float4 p0 = p[0], p1 = p[1], p2 = p[2], p3 = p[3];
        float s = (p0.x + p0.y + p0.z + p0.w) + (p1.x + p1.y + p1.z + p1.w)
                + (p2.x + p2.y + p2.z + p2.w) + (p3.x + p3.y + p3.z + p3.w);
        local = log2f(s) - diag[row];
    }
    red[threadIdx.x] = local;
    __syncthreads();
    for (int off = 128; off > 0; off >>= 1) {
        if (threadIdx.x < off) red[threadIdx.x] += red[threadIdx.x + off];
        __syncthreads();
    }
    if (threadIdx.x == 0) bsum[blockIdx.x] = red[0];
}

// Kernel 3b: final reduce of block sums -> loss.
__global__ __launch_bounds__(64) void final_kernel(
    const float* __restrict__ bsum, float* __restrict__ out, int nblocks, int n)
{
    float v = (threadIdx.x < nblocks) ? bsum[threadIdx.x] : 0.0f;
#pragma unroll
    for (int m = 1; m < 64; m <<= 1) v += __shfl_xor(v, m, 64);
    if (threadIdx.x == 0) out[0] = v * (LN2 / (float)n);
}

extern "C" void kernel_launch(void* const* d_in, const int* in_sizes, int n_in,
                              void* d_out, int out_size, void* d_ws, size_t ws_size,
                              hipStream_t stream) {
    const int n = in_sizes[0] / DIM;  // 8192
    const float* A = (const float*)d_in[0];
    const float* B = (const float*)d_in[1];
    float* out = (float*)d_out;

    // workspace layout
    unsigned short* Abf = (unsigned short*)d_ws;                 // n*DIM bf16
    unsigned short* Bbf = Abf + (size_t)n * DIM;                 // n*DIM bf16
    float* partial = (float*)(Bbf + (size_t)n * DIM);            // n*16 f32 (row-major)
    float* diag = partial + (size_t)n * 16;                      // n f32
    float* bsum = diag + n;                                      // 32 f32

    normalize_kernel<<<n / 4, 256, 0, stream>>>(A, B, Abf, Bbf, diag, n);

    dim3 grid(n / 64, 4);
    gemm_lse_kernel<<<grid, 256, 0, stream>>>(Abf, Bbf, partial, n);

    const int nred = (n + 255) / 256;  // 32
    row_lse_kernel<<<nred, 256, 0, stream>>>(partial, diag, bsum, n);
    final_kernel<<<1, 64, 0, stream>>>(bsum, out, nred, n);
}

// Round 4
// 137.289 us; speedup vs baseline: 1.6860x; 1.0000x over previous
//
#include <hip/hip_runtime.h>
#include <hip/hip_bf16.h>
#include <math.h>

#define DIM 256

typedef __bf16 bf16x8 __attribute__((ext_vector_type(8)));
typedef float f32x4 __attribute__((ext_vector_type(4)));

__constant__ const float kTempInvLog2e = 20.0f * 1.4426950408889634f; // (1/temp)*log2(e)
#define LN2 0.6931471805599453f
#define EPS_NORM 1e-8f

// round-to-nearest-even f32 -> bf16 bits
static __device__ inline unsigned short f2bf(float f) {
    unsigned u = __builtin_bit_cast(unsigned, f);
    unsigned r = (u + 0x7fffu + ((u >> 16) & 1u)) >> 16;
    return (unsigned short)r;
}

// Kernel 1: per-row L2 normalize of BOTH A and B, emit bf16, plus
// diag[r] = cos(a_r,b_r)*(1/temp)*log2(e). 4 rows per 256-thr block (1 wave/row).
__global__ __launch_bounds__(256) void normalize_kernel(
    const float* __restrict__ A, const float* __restrict__ B,
    unsigned short* __restrict__ Abf, unsigned short* __restrict__ Bbf,
    float* __restrict__ diag, int n)
{
    const int r = blockIdx.x * 4 + (threadIdx.x >> 6);
    const int lane = threadIdx.x & 63;
    float4 a = ((const float4*)(A + (size_t)r * DIM))[lane];
    float4 b = ((const float4*)(B + (size_t)r * DIM))[lane];

    float ssa = a.x * a.x + a.y * a.y + a.z * a.z + a.w * a.w;
    float ssb = b.x * b.x + b.y * b.y + b.z * b.z + b.w * b.w;
    float dd  = a.x * b.x + a.y * b.y + a.z * b.z + a.w * b.w;
#pragma unroll
    for (int m = 1; m < 64; m <<= 1) {
        ssa += __shfl_xor(ssa, m, 64);
        ssb += __shfl_xor(ssb, m, 64);
        dd  += __shfl_xor(dd, m, 64);
    }
    float na = fmaxf(sqrtf(ssa), EPS_NORM);
    float nb = fmaxf(sqrtf(ssb), EPS_NORM);
    float sa = kTempInvLog2e / na;
    float sb = 1.0f / nb;

    ushort4 oa, ob;
    oa.x = f2bf(a.x * sa); oa.y = f2bf(a.y * sa); oa.z = f2bf(a.z * sa); oa.w = f2bf(a.w * sa);
    ob.x = f2bf(b.x * sb); ob.y = f2bf(b.y * sb); ob.z = f2bf(b.z * sb); ob.w = f2bf(b.w * sb);
    ((ushort4*)(Abf + (size_t)r * DIM))[lane] = oa;
    ((ushort4*)(Bbf + (size_t)r * DIM))[lane] = ob;

    if (lane == 0) diag[r] = dd / (na * nb) * kTempInvLog2e;
}

#define LOAD_B(buf, ptr)                                   \
    _Pragma("unroll")                                      \
    for (int k = 0; k < 8; ++k)                            \
        buf[k] = *(const bf16x8*)((ptr) + k * 32);

#define COMPUTE_TILE(buf)                                  \
    {                                                      \
        f32x4 acc[4];                                      \
        _Pragma("unroll")                                  \
        for (int t = 0; t < 4; ++t) acc[t] = (f32x4){0.f, 0.f, 0.f, 0.f}; \
        _Pragma("unroll")                                  \
        for (int k = 0; k < 8; ++k) {                      \
            _Pragma("unroll")                              \
            for (int t = 0; t < 4; ++t)                    \
                acc[t] = __builtin_amdgcn_mfma_f32_16x16x32_bf16( \
                    afrag[t][k], buf[k], acc[t], 0, 0, 0); \
        }                                                  \
        _Pragma("unroll")                                  \
        for (int t = 0; t < 4; ++t) {                      \
            _Pragma("unroll")                              \
            for (int r = 0; r < 4; ++r)                    \
                sums[t * 4 + r] += __builtin_amdgcn_exp2f(acc[t][r]); \
        }                                                  \
    }

// Kernel 2: fused GEMM (bf16 MFMA 16x16x32) + exp2 + per-row partial sums.
// Block = 512 thr (8 waves) covering 128 rows x (n/4) cols:
//   wave w: row-half rh = w>>2 (64 rows), col-slice cs = w&3 (16 of each 64-col tile).
// Each wave keeps its 64xK A fragments in registers (pinned; allocator may use
// AGPRs — legal MFMA A operands on gfx950) and double-buffers B in registers.
// XCD-pinned scheduling: linear grid, xcd = blk&7 -> fixed column split
// (split = xcd>>1), so each XCD re-reads only a 1 MB B-slice (L2-resident).
// M-tile 128 halves total B traffic vs R3 (512 -> 256 MB).
__global__ __launch_bounds__(512, 2) void gemm_lse_kernel(
    const unsigned short* __restrict__ Abf, const unsigned short* __restrict__ Bbf,
    float* __restrict__ partial, int n)
{
    const int lane = threadIdx.x & 63;
    const int w = threadIdx.x >> 6;       // 0..7
    const int cs = w & 3;                 // column slice within 64-col tile
    const int rh = w >> 2;                // row half (0/1)
    const int c = lane & 15;              // M index (A), N index (B), col (C/D)
    const int q = lane >> 4;              // K-chunk (A,B); row-quad (C/D)

    // block decode: i = j*8 + xcd;  xcd -> (split, rowblk-half)
    const int i = blockIdx.x;
    const int xcd = i & 7;
    const int split = xcd >> 1;           // 0..3, fixed per XCD
    const int sub = xcd & 1;
    const int j = i >> 3;
    const int nrowblk = n / 128;          // 64
    const int rowblk = sub * (nrowblk / 2) + j;
    const int rowbase = rowblk * 128 + rh * 64;
    const int ncols = n >> 2;             // cols per split (2048)
    const int colstart = split * ncols;

    // persistent A fragments: 4 Mtiles x 8 Ksteps x 16B = 128 regs
    bf16x8 afrag[4][8];
#pragma unroll
    for (int t = 0; t < 4; ++t) {
        const unsigned short* ap = Abf + (size_t)(rowbase + t * 16 + c) * DIM + q * 8;
#pragma unroll
        for (int k = 0; k < 8; ++k)
            afrag[t][k] = *(const bf16x8*)(ap + k * 32);
    }
    // pin: forces the loads above to complete here and stay materialized
#pragma unroll
    for (int t = 0; t < 4; ++t)
#pragma unroll
        for (int k = 0; k < 8; ++k)
            asm volatile("" : "+v"(*(f32x4*)&afrag[t][k]));

    float sums[16];
#pragma unroll
    for (int i2 = 0; i2 < 16; ++i2) sums[i2] = 0.0f;

    const unsigned short* bp0 = Bbf + (size_t)(colstart + cs * 16 + c) * DIM + q * 8;
    const int niter = ncols / 64;   // 32 for n=8192 (even)

    // explicit register double-buffer, compile-time indices only
    bf16x8 b0[8], b1[8];
    LOAD_B(b0, bp0);

    for (int it = 0; it < niter; it += 2) {
        const unsigned short* bpn1 = bp0 + (size_t)(it + 1) * 64 * DIM;
        LOAD_B(b1, bpn1);          // prefetch tile it+1
        COMPUTE_TILE(b0);          // compute tile it

        const unsigned short* bpn2 = bp0 + (size_t)(it + 2) * 64 * DIM;
        LOAD_B(b0, bpn2);          // prefetch tile it+2 (tail read stays in ws)
        COMPUTE_TILE(b1);          // compute tile it+1
    }

    // reduce each row sum across the 16 lanes of its q-group (cols mod 16)
#pragma unroll
    for (int i2 = 0; i2 < 16; ++i2) {
        float s = sums[i2];
        s += __shfl_xor(s, 1, 64);
        s += __shfl_xor(s, 2, 64);
        s += __shfl_xor(s, 4, 64);
        s += __shfl_xor(s, 8, 64);
        sums[i2] = s;
    }
    if (c == 0) {
        const int p = split * 4 + cs;
#pragma unroll
        for (int t = 0; t < 4; ++t)
#pragma unroll
            for (int r = 0; r < 4; ++r)
                partial[(size_t)(rowbase + t * 16 + q * 4 + r) * 16 + p] = sums[t * 4 + r];
    }
}

// Kernel 3a: per-row lse - diag, block-reduced. One row per thread, 32 blocks.
__global__ __launch_bounds__(256) void row_lse_kernel(
    const float* __restrict__ partial, const float* __restrict__ diag,
    float* __restrict__ bsum, int n)
{
    __shared__ float red[256];
    const int row = blockIdx.x * 256 + threadIdx.x;
    float local = 0.0f;
    if (row < n) {
        const float4* p = (const float4*)(partial + (size_t)row * 16);
        float4 p0 = p[0], p1 = p[1], p2 = p[2], p3 = p[3];
        float s = (p0.x + p0.y + p0.z + p0.w) + (p1.x + p1.y + p1.z + p1.w)
                + (p2.x + p2.y + p2.z + p2.w) + (p3.x + p3.y + p3.z + p3.w);
        local = log2f(s) - diag[row];
    }
    red[threadIdx.x] = local;
    __syncthreads();
    for (int off = 128; off > 0; off >>= 1) {
        if (threadIdx.x < off) red[threadIdx.x] += red[threadIdx.x + off];
        __syncthreads();
    }
    if (threadIdx.x == 0) bsum[blockIdx.x] = red[0];
}

// Kernel 3b: final reduce of block sums -> loss.
__global__ __launch_bounds__(64) void final_kernel(
    const float* __restrict__ bsum, float* __restrict__ out, int nblocks, int n)
{
    float v = (threadIdx.x < nblocks) ? bsum[threadIdx.x] : 0.0f;
#pragma unroll
    for (int m = 1; m < 64; m <<= 1) v += __shfl_xor(v, m, 64);
    if (threadIdx.x == 0) out[0] = v * (LN2 / (float)n);
}

extern "C" void kernel_launch(void* const* d_in, const int* in_sizes, int n_in,
                              void* d_out, int out_size, void* d_ws, size_t ws_size,
                              hipStream_t stream) {
    const int n = in_sizes[0] / DIM;  // 8192
    const float* A = (const float*)d_in[0];
    const float* B = (const float*)d_in[1];
    float* out = (float*)d_out;

    // workspace layout
    unsigned short* Abf = (unsigned short*)d_ws;                 // n*DIM bf16
    unsigned short* Bbf = Abf + (size_t)n * DIM;                 // n*DIM bf16
    float* partial = (float*)(Bbf + (size_t)n * DIM);            // n*16 f32 (row-major)
    float* diag = partial + (size_t)n * 16;                      // n f32
    float* bsum = diag + n;                                      // 32 f32

    normalize_kernel<<<n / 4, 256, 0, stream>>>(A, B, Abf, Bbf, diag, n);

    // linear grid: (n/128 row-blocks) x (4 splits), XCD-decoded in-kernel
    gemm_lse_kernel<<<(n / 128) * 4, 512, 0, stream>>>(Abf, Bbf, partial, n);

    const int nred = (n + 255) / 256;  // 32
    row_lse_kernel<<<nred, 256, 0, stream>>>(partial, diag, bsum, n);
    final_kernel<<<1, 64, 0, stream>>>(bsum, out, nred, n);
}

// Round 5
// 104.292 us; speedup vs baseline: 2.2194x; 1.3164x over previous
//
#include <hip/hip_runtime.h>
#include <hip/hip_bf16.h>
#include <math.h>

#define DIM 256

typedef __bf16 bf16x8 __attribute__((ext_vector_type(8)));
typedef float f32x4 __attribute__((ext_vector_type(4)));

__constant__ const float kTempInvLog2e = 20.0f * 1.4426950408889634f; // (1/temp)*log2(e)
#define LN2 0.6931471805599453f
#define EPS_NORM 1e-8f

// round-to-nearest-even f32 -> bf16 bits
static __device__ inline unsigned short f2bf(float f) {
    unsigned u = __builtin_bit_cast(unsigned, f);
    unsigned r = (u + 0x7fffu + ((u >> 16) & 1u)) >> 16;
    return (unsigned short)r;
}
static __device__ inline unsigned pack2(float x, float y, float s) {
    return (unsigned)f2bf(x * s) | ((unsigned)f2bf(y * s) << 16);
}

// async 16B/lane global->LDS copy. lds base is wave-uniform; HW adds lane*16.
static __device__ inline void async_copy16(const void* g, void* l) {
    __builtin_amdgcn_global_load_lds(
        (const __attribute__((address_space(1))) unsigned int*)g,
        (__attribute__((address_space(3))) unsigned int*)l, 16, 0, 0);
}

// Kernel 1: normalize + quantize + PACK to fragment-major granule layout.
// Granule g = 16 B = 8 bf16. Packed index for 16-row tile T:
//   idx = T*512 + k*64 + lane, lane = rowlocal + 16*q, holding
//   X[row=T*16+rowlocal][k*32 + q*8 .. +8]  -- exactly the MFMA A/B fragment.
// Block = 256 thr handles 16 rows of BOTH A and B (thread t: row t>>4, elems (t&15)*16..+16).
// Also computes diag[r] = cos(a_r,b_r)*(1/temp)*log2(e).
__global__ __launch_bounds__(256) void normpack_kernel(
    const float* __restrict__ A, const float* __restrict__ B,
    unsigned short* __restrict__ Apk, unsigned short* __restrict__ Bpk,
    float* __restrict__ diag, int n)
{
    __shared__ uint4 lA[512];
    __shared__ uint4 lB[512];
    const int t = threadIdx.x;
    const int rl = t >> 4;       // row-local 0..15
    const int c16 = t & 15;      // 16-elem chunk 0..15
    const int r = blockIdx.x * 16 + rl;

    const float4* pa = (const float4*)(A + (size_t)r * DIM + c16 * 16);
    const float4* pb = (const float4*)(B + (size_t)r * DIM + c16 * 16);
    float4 a0 = pa[0], a1 = pa[1], a2 = pa[2], a3 = pa[3];
    float4 b0 = pb[0], b1 = pb[1], b2 = pb[2], b3 = pb[3];

    float ssa = a0.x*a0.x + a0.y*a0.y + a0.z*a0.z + a0.w*a0.w
              + a1.x*a1.x + a1.y*a1.y + a1.z*a1.z + a1.w*a1.w
              + a2.x*a2.x + a2.y*a2.y + a2.z*a2.z + a2.w*a2.w
              + a3.x*a3.x + a3.y*a3.y + a3.z*a3.z + a3.w*a3.w;
    float ssb = b0.x*b0.x + b0.y*b0.y + b0.z*b0.z + b0.w*b0.w
              + b1.x*b1.x + b1.y*b1.y + b1.z*b1.z + b1.w*b1.w
              + b2.x*b2.x + b2.y*b2.y + b2.z*b2.z + b2.w*b2.w
              + b3.x*b3.x + b3.y*b3.y + b3.z*b3.z + b3.w*b3.w;
    float dd  = a0.x*b0.x + a0.y*b0.y + a0.z*b0.z + a0.w*b0.w
              + a1.x*b1.x + a1.y*b1.y + a1.z*b1.z + a1.w*b1.w
              + a2.x*b2.x + a2.y*b2.y + a2.z*b2.z + a2.w*b2.w
              + a3.x*b3.x + a3.y*b3.y + a3.z*b3.z + a3.w*b3.w;
#pragma unroll
    for (int m = 1; m < 16; m <<= 1) {
        ssa += __shfl_xor(ssa, m, 64);
        ssb += __shfl_xor(ssb, m, 64);
        dd  += __shfl_xor(dd, m, 64);
    }
    float na = fmaxf(sqrtf(ssa), EPS_NORM);
    float nb = fmaxf(sqrtf(ssb), EPS_NORM);
    float sa = kTempInvLog2e / na;
    float sb = 1.0f / nb;
    if (c16 == 0) diag[r] = dd / (na * nb) * kTempInvLog2e;

    // granules m0=2*c16 (elems a0,a1) and m1=m0+1 (a2,a3); pos = k*64 + rl + q*16
    const int k0 = c16 >> 1;
    const int q0 = (c16 & 1) * 2;
    const int p0 = k0 * 64 + rl + q0 * 16;   // p1 = p0 + 16
    uint4 ga0, ga1, gb0, gb1;
    ga0.x = pack2(a0.x, a0.y, sa); ga0.y = pack2(a0.z, a0.w, sa);
    ga0.z = pack2(a1.x, a1.y, sa); ga0.w = pack2(a1.z, a1.w, sa);
    ga1.x = pack2(a2.x, a2.y, sa); ga1.y = pack2(a2.z, a2.w, sa);
    ga1.z = pack2(a3.x, a3.y, sa); ga1.w = pack2(a3.z, a3.w, sa);
    gb0.x = pack2(b0.x, b0.y, sb); gb0.y = pack2(b0.z, b0.w, sb);
    gb0.z = pack2(b1.x, b1.y, sb); gb0.w = pack2(b1.z, b1.w, sb);
    gb1.x = pack2(b2.x, b2.y, sb); gb1.y = pack2(b2.z, b2.w, sb);
    gb1.z = pack2(b3.x, b3.y, sb); gb1.w = pack2(b3.z, b3.w, sb);
    lA[p0] = ga0; lA[p0 + 16] = ga1;
    lB[p0] = gb0; lB[p0 + 16] = gb1;
    __syncthreads();

    // coalesced write-out: thread t stores granules 2t, 2t+1 (32 B contiguous)
    const size_t gbase = (size_t)blockIdx.x * 512 + 2 * t;
    ((uint4*)Apk)[gbase]     = lA[2 * t];
    ((uint4*)Apk)[gbase + 1] = lA[2 * t + 1];
    ((uint4*)Bpk)[gbase]     = lB[2 * t];
    ((uint4*)Bpk)[gbase + 1] = lB[2 * t + 1];
}

// Kernel 2: fused GEMM + exp2 + per-row partial sums.
// Block = 256 thr (4 waves). Block tile = 128 rows x 512 cols (1 of 16 splits).
// Wave w owns rows rowblk*128 + w*32 .. +32 (A fragments in regs, 64 VGPRs).
// B streamed as 32-col tiles (16 KB packed, contiguous) through LDS double
// buffer via async global_load_lds; all 4 waves share each tile via ds_read_b128.
// Grid = 64 rowblocks x 16 splits = 1024 blocks (4/CU). split<->XCD pinned:
// split = (i&7) + 8*((i>>3)&1) so each XCD touches a 1 MB B-slice (L2-resident).
__global__ __launch_bounds__(256, 3) void gemm_lse_kernel(
    const unsigned short* __restrict__ Apk, const unsigned short* __restrict__ Bpk,
    float* __restrict__ partial, int n)
{
    __shared__ char ldsbuf[32768];   // 2 x 16 KB B-tile double buffer
    const int lane = threadIdx.x & 63;
    const int w = threadIdx.x >> 6;
    const int c = lane & 15;
    const int q = lane >> 4;

    const int i = blockIdx.x;
    const int split = (i & 7) + 8 * ((i >> 3) & 1);  // 0..15
    const int rowblk = i >> 4;                        // 0..63
    const int rowbase = rowblk * 128 + w * 32;

    // A fragments: 2 row-tiles of 16 (32 rows/wave), coalesced granule loads
    bf16x8 afrag[2][8];
    const int atile0 = rowblk * 8 + w * 2;
#pragma unroll
    for (int m = 0; m < 2; ++m)
#pragma unroll
        for (int k = 0; k < 8; ++k)
            afrag[m][k] = *(const bf16x8*)(Apk + ((size_t)(atile0 + m) * 512 + k * 64 + lane) * 8);
#pragma unroll
    for (int m = 0; m < 2; ++m)
#pragma unroll
        for (int k = 0; k < 8; ++k)
            asm volatile("" : "+v"(*(f32x4*)&afrag[m][k]));  // keep resident

    float sums[8];
#pragma unroll
    for (int s = 0; s < 8; ++s) sums[s] = 0.0f;

    const char* bbase = (const char*)Bpk + (size_t)(split * 32) * 8192; // 256 KB slice
    const int niter = n / 512;   // 16

    // stage tile 0 into buffer 0 (each wave copies its 4 KB quarter)
    {
        const char* src = bbase + w * 4096 + (size_t)lane * 16;
        char* dst = ldsbuf + w * 4096;
#pragma unroll
        for (int j = 0; j < 4; ++j)
            async_copy16(src + j * 1024, dst + j * 1024);
    }
    __syncthreads();   // drains vmcnt

    for (int it = 0; it < niter; ++it) {
        const int cur = it & 1;
        if (it + 1 < niter) {   // async prefetch next tile into the other buffer
            const char* src = bbase + (size_t)(it + 1) * 16384 + w * 4096 + (size_t)lane * 16;
            char* dst = ldsbuf + (cur ^ 1) * 16384 + w * 4096;
#pragma unroll
            for (int j = 0; j < 4; ++j)
                async_copy16(src + j * 1024, dst + j * 1024);
        }

        f32x4 acc[2][2];
#pragma unroll
        for (int m = 0; m < 2; ++m)
#pragma unroll
            for (int nn = 0; nn < 2; ++nn)
                acc[m][nn] = (f32x4){0.f, 0.f, 0.f, 0.f};

        const char* lb = ldsbuf + cur * 16384 + (size_t)lane * 16;
#pragma unroll
        for (int k = 0; k < 8; ++k) {
            bf16x8 bv0 = *(const bf16x8*)(lb + k * 1024);
            bf16x8 bv1 = *(const bf16x8*)(lb + 8192 + k * 1024);
#pragma unroll
            for (int m = 0; m < 2; ++m) {
                acc[m][0] = __builtin_amdgcn_mfma_f32_16x16x32_bf16(afrag[m][k], bv0, acc[m][0], 0, 0, 0);
                acc[m][1] = __builtin_amdgcn_mfma_f32_16x16x32_bf16(afrag[m][k], bv1, acc[m][1], 0, 0, 0);
            }
        }

#pragma unroll
        for (int m = 0; m < 2; ++m)
#pragma unroll
            for (int nn = 0; nn < 2; ++nn)
#pragma unroll
                for (int r = 0; r < 4; ++r)
                    sums[m * 4 + r] += __builtin_amdgcn_exp2f(acc[m][nn][r]);

        __syncthreads();   // staging of it+1 complete; all waves done with cur
    }

    // reduce row sums across the 16 lanes of each q-group
#pragma unroll
    for (int s = 0; s < 8; ++s) {
        float v = sums[s];
        v += __shfl_xor(v, 1, 64);
        v += __shfl_xor(v, 2, 64);
        v += __shfl_xor(v, 4, 64);
        v += __shfl_xor(v, 8, 64);
        sums[s] = v;
    }
    if (c == 0) {
#pragma unroll
        for (int m = 0; m < 2; ++m)
#pragma unroll
            for (int r = 0; r < 4; ++r)
                partial[(size_t)(rowbase + m * 16 + q * 4 + r) * 16 + split] = sums[m * 4 + r];
    }
}

// Kernel 3a: per-row lse - diag, block-reduced. One row per thread, 32 blocks.
__global__ __launch_bounds__(256) void row_lse_kernel(
    const float* __restrict__ partial, const float* __restrict__ diag,
    float* __restrict__ bsum, int n)
{
    __shared__ float red[256];
    const int row = blockIdx.x * 256 + threadIdx.x;
    float local = 0.0f;
    if (row < n) {
        const float4* p = (const float4*)(partial + (size_t)row * 16);
        float4 p0 = p[0], p1 = p[1], p2 = p[2], p3 = p[3];
        float s = (p0.x + p0.y + p0.z + p0.w) + (p1.x + p1.y + p1.z + p1.w)
                + (p2.x + p2.y + p2.z + p2.w) + (p3.x + p3.y + p3.z + p3.w);
        local = log2f(s) - diag[row];
    }
    red[threadIdx.x] = local;
    __syncthreads();
    for (int off = 128; off > 0; off >>= 1) {
        if (threadIdx.x < off) red[threadIdx.x] += red[threadIdx.x + off];
        __syncthreads();
    }
    if (threadIdx.x == 0) bsum[blockIdx.x] = red[0];
}

// Kernel 3b: final reduce of block sums -> loss.
__global__ __launch_bounds__(64) void final_kernel(
    const float* __restrict__ bsum, float* __restrict__ out, int nblocks, int n)
{
    float v = (threadIdx.x < nblocks) ? bsum[threadIdx.x] : 0.0f;
#pragma unroll
    for (int m = 1; m < 64; m <<= 1) v += __shfl_xor(v, m, 64);
    if (threadIdx.x == 0) out[0] = v * (LN2 / (float)n);
}

extern "C" void kernel_launch(void* const* d_in, const int* in_sizes, int n_in,
                              void* d_out, int out_size, void* d_ws, size_t ws_size,
                              hipStream_t stream) {
    const int n = in_sizes[0] / DIM;  // 8192
    const float* A = (const float*)d_in[0];
    const float* B = (const float*)d_in[1];
    float* out = (float*)d_out;

    // workspace layout
    unsigned short* Apk = (unsigned short*)d_ws;                 // n*DIM bf16 (packed granules)
    unsigned short* Bpk = Apk + (size_t)n * DIM;                 // n*DIM bf16 (packed granules)
    float* partial = (float*)(Bpk + (size_t)n * DIM);            // n*16 f32 (row-major)
    float* diag = partial + (size_t)n * 16;                      // n f32
    float* bsum = diag + n;                                      // 32 f32

    normpack_kernel<<<n / 16, 256, 0, stream>>>(A, B, Apk, Bpk, diag, n);

    // 64 rowblocks x 16 splits, XCD-decoded in-kernel
    gemm_lse_kernel<<<(n / 128) * 16, 256, 0, stream>>>(Apk, Bpk, partial, n);

    const int nred = (n + 255) / 256;  // 32
    row_lse_kernel<<<nred, 256, 0, stream>>>(partial, diag, bsum, n);
    final_kernel<<<1, 64, 0, stream>>>(bsum, out, nred, n);
}

// Round 6
// 103.288 us; speedup vs baseline: 2.2410x; 1.0097x over previous
//
#include <hip/hip_runtime.h>
#include <hip/hip_bf16.h>
#include <math.h>

#define DIM 256

typedef __bf16 bf16x8 __attribute__((ext_vector_type(8)));
typedef float f32x4 __attribute__((ext_vector_type(4)));

__constant__ const float kTempInvLog2e = 20.0f * 1.4426950408889634f; // (1/temp)*log2(e)
#define LN2 0.6931471805599453f
#define EPS_NORM 1e-8f

// round-to-nearest-even f32 -> bf16 bits
static __device__ inline unsigned short f2bf(float f) {
    unsigned u = __builtin_bit_cast(unsigned, f);
    unsigned r = (u + 0x7fffu + ((u >> 16) & 1u)) >> 16;
    return (unsigned short)r;
}
static __device__ inline unsigned pack2(float x, float y, float s) {
    return (unsigned)f2bf(x * s) | ((unsigned)f2bf(y * s) << 16);
}

// async 16B/lane global->LDS copy. lds base is wave-uniform; HW adds lane*16.
static __device__ inline void async_copy16(const void* g, void* l) {
    __builtin_amdgcn_global_load_lds(
        (const __attribute__((address_space(1))) unsigned int*)g,
        (__attribute__((address_space(3))) unsigned int*)l, 16, 0, 0);
}

// Kernel 1: normalize + quantize + PACK to fragment-major granule layout.
// Granule g = 16 B = 8 bf16. Packed index for 16-row tile T:
//   idx = T*512 + k*64 + lane, lane = rowlocal + 16*q, holding
//   X[row=T*16+rowlocal][k*32 + q*8 .. +8]  -- exactly the MFMA A/B fragment.
// Block = 256 thr handles 16 rows of BOTH A and B. Also diag[r].
__global__ __launch_bounds__(256) void normpack_kernel(
    const float* __restrict__ A, const float* __restrict__ B,
    unsigned short* __restrict__ Apk, unsigned short* __restrict__ Bpk,
    float* __restrict__ diag, int n)
{
    __shared__ uint4 lA[512];
    __shared__ uint4 lB[512];
    const int t = threadIdx.x;
    const int rl = t >> 4;       // row-local 0..15
    const int c16 = t & 15;      // 16-elem chunk 0..15
    const int r = blockIdx.x * 16 + rl;

    const float4* pa = (const float4*)(A + (size_t)r * DIM + c16 * 16);
    const float4* pb = (const float4*)(B + (size_t)r * DIM + c16 * 16);
    float4 a0 = pa[0], a1 = pa[1], a2 = pa[2], a3 = pa[3];
    float4 b0 = pb[0], b1 = pb[1], b2 = pb[2], b3 = pb[3];

    float ssa = a0.x*a0.x + a0.y*a0.y + a0.z*a0.z + a0.w*a0.w
              + a1.x*a1.x + a1.y*a1.y + a1.z*a1.z + a1.w*a1.w
              + a2.x*a2.x + a2.y*a2.y + a2.z*a2.z + a2.w*a2.w
              + a3.x*a3.x + a3.y*a3.y + a3.z*a3.z + a3.w*a3.w;
    float ssb = b0.x*b0.x + b0.y*b0.y + b0.z*b0.z + b0.w*b0.w
              + b1.x*b1.x + b1.y*b1.y + b1.z*b1.z + b1.w*b1.w
              + b2.x*b2.x + b2.y*b2.y + b2.z*b2.z + b2.w*b2.w
              + b3.x*b3.x + b3.y*b3.y + b3.z*b3.z + b3.w*b3.w;
    float dd  = a0.x*b0.x + a0.y*b0.y + a0.z*b0.z + a0.w*b0.w
              + a1.x*b1.x + a1.y*b1.y + a1.z*b1.z + a1.w*b1.w
              + a2.x*b2.x + a2.y*b2.y + a2.z*b2.z + a2.w*b2.w
              + a3.x*b3.x + a3.y*b3.y + a3.z*b3.z + a3.w*b3.w;
#pragma unroll
    for (int m = 1; m < 16; m <<= 1) {
        ssa += __shfl_xor(ssa, m, 64);
        ssb += __shfl_xor(ssb, m, 64);
        dd  += __shfl_xor(dd, m, 64);
    }
    float na = fmaxf(sqrtf(ssa), EPS_NORM);
    float nb = fmaxf(sqrtf(ssb), EPS_NORM);
    float sa = kTempInvLog2e / na;
    float sb = 1.0f / nb;
    if (c16 == 0) diag[r] = dd / (na * nb) * kTempInvLog2e;

    const int k0 = c16 >> 1;
    const int q0 = (c16 & 1) * 2;
    const int p0 = k0 * 64 + rl + q0 * 16;   // p1 = p0 + 16
    uint4 ga0, ga1, gb0, gb1;
    ga0.x = pack2(a0.x, a0.y, sa); ga0.y = pack2(a0.z, a0.w, sa);
    ga0.z = pack2(a1.x, a1.y, sa); ga0.w = pack2(a1.z, a1.w, sa);
    ga1.x = pack2(a2.x, a2.y, sa); ga1.y = pack2(a2.z, a2.w, sa);
    ga1.z = pack2(a3.x, a3.y, sa); ga1.w = pack2(a3.z, a3.w, sa);
    gb0.x = pack2(b0.x, b0.y, sb); gb0.y = pack2(b0.z, b0.w, sb);
    gb0.z = pack2(b1.x, b1.y, sb); gb0.w = pack2(b1.z, b1.w, sb);
    gb1.x = pack2(b2.x, b2.y, sb); gb1.y = pack2(b2.z, b2.w, sb);
    gb1.z = pack2(b3.x, b3.y, sb); gb1.w = pack2(b3.z, b3.w, sb);
    lA[p0] = ga0; lA[p0 + 16] = ga1;
    lB[p0] = gb0; lB[p0 + 16] = gb1;
    __syncthreads();

    const size_t gbase = (size_t)blockIdx.x * 512 + 2 * t;
    ((uint4*)Apk)[gbase]     = lA[2 * t];
    ((uint4*)Apk)[gbase + 1] = lA[2 * t + 1];
    ((uint4*)Bpk)[gbase]     = lB[2 * t];
    ((uint4*)Bpk)[gbase + 1] = lB[2 * t + 1];
}

// Kernel 2: fused GEMM + exp2 + per-row partial sums.
// Block = 256 thr (4 waves). Block tile = 256 rows x 512 cols (1 of 16 splits).
// Wave w owns rows rowblk*256 + w*64 .. +64: A fragments pinned in regs
// (4 row-tiles x 8 k = 128 regs). B streamed as 32-col packed tiles (16 KB)
// through an LDS double buffer via async global_load_lds; each wave reads the
// full tile, feeding each 16B B-fragment to 4 MFMAs (half the LDS traffic of
// the 32-row variant; matrix pipe becomes the binding resource).
// Grid = 32 rowblocks x 16 splits = 512 blocks (2/CU). split<->XCD pinned:
// split = (i&7) + 8*((i>>3)&1) so each XCD touches a 512 KB B-slice (L2-res).
__global__ __launch_bounds__(256, 2) void gemm_lse_kernel(
    const unsigned short* __restrict__ Apk, const unsigned short* __restrict__ Bpk,
    float* __restrict__ partial, int n)
{
    __shared__ char ldsbuf[32768];   // 2 x 16 KB B-tile double buffer
    const int lane = threadIdx.x & 63;
    const int w = threadIdx.x >> 6;
    const int c = lane & 15;
    const int q = lane >> 4;

    const int i = blockIdx.x;
    const int split = (i & 7) + 8 * ((i >> 3) & 1);  // 0..15
    const int rowblk = i >> 4;                        // 0..31
    const int rowbase = rowblk * 256 + w * 64;

    // A fragments: 4 row-tiles of 16 (64 rows/wave), coalesced granule loads
    bf16x8 afrag[4][8];
    const int atile0 = rowblk * 16 + w * 4;
#pragma unroll
    for (int m = 0; m < 4; ++m)
#pragma unroll
        for (int k = 0; k < 8; ++k)
            afrag[m][k] = *(const bf16x8*)(Apk + ((size_t)(atile0 + m) * 512 + k * 64 + lane) * 8);
#pragma unroll
    for (int m = 0; m < 4; ++m)
#pragma unroll
        for (int k = 0; k < 8; ++k)
            asm volatile("" : "+v"(*(f32x4*)&afrag[m][k]));  // keep resident

    float sums[16];
#pragma unroll
    for (int s = 0; s < 16; ++s) sums[s] = 0.0f;

    const char* bbase = (const char*)Bpk + (size_t)(split * 32) * 8192; // 256 KB slice
    const int niter = n / 512;   // 16 tiles of 32 cols

    // stage tile 0 into buffer 0 (each wave copies its 4 KB quarter)
    {
        const char* src = bbase + w * 4096 + (size_t)lane * 16;
        char* dst = ldsbuf + w * 4096;
#pragma unroll
        for (int j = 0; j < 4; ++j)
            async_copy16(src + j * 1024, dst + j * 1024);
    }
    __syncthreads();   // drains vmcnt

    for (int it = 0; it < niter; ++it) {
        const int cur = it & 1;
        if (it + 1 < niter) {   // async prefetch next tile into the other buffer
            const char* src = bbase + (size_t)(it + 1) * 16384 + w * 4096 + (size_t)lane * 16;
            char* dst = ldsbuf + (cur ^ 1) * 16384 + w * 4096;
#pragma unroll
            for (int j = 0; j < 4; ++j)
                async_copy16(src + j * 1024, dst + j * 1024);
        }

        f32x4 acc[4][2];
#pragma unroll
        for (int m = 0; m < 4; ++m)
#pragma unroll
            for (int nn = 0; nn < 2; ++nn)
                acc[m][nn] = (f32x4){0.f, 0.f, 0.f, 0.f};

        const char* lb = ldsbuf + cur * 16384 + (size_t)lane * 16;
#pragma unroll
        for (int k = 0; k < 8; ++k) {
            bf16x8 bv0 = *(const bf16x8*)(lb + k * 1024);
            bf16x8 bv1 = *(const bf16x8*)(lb + 8192 + k * 1024);
#pragma unroll
            for (int m = 0; m < 4; ++m) {
                acc[m][0] = __builtin_amdgcn_mfma_f32_16x16x32_bf16(afrag[m][k], bv0, acc[m][0], 0, 0, 0);
                acc[m][1] = __builtin_amdgcn_mfma_f32_16x16x32_bf16(afrag[m][k], bv1, acc[m][1], 0, 0, 0);
            }
        }

#pragma unroll
        for (int m = 0; m < 4; ++m)
#pragma unroll
            for (int nn = 0; nn < 2; ++nn)
#pragma unroll
                for (int r = 0; r < 4; ++r)
                    sums[m * 4 + r] += __builtin_amdgcn_exp2f(acc[m][nn][r]);

        __syncthreads();   // staging of it+1 complete; all waves done with cur
    }

    // reduce row sums across the 16 lanes of each q-group
#pragma unroll
    for (int s = 0; s < 16; ++s) {
        float v = sums[s];
        v += __shfl_xor(v, 1, 64);
        v += __shfl_xor(v, 2, 64);
        v += __shfl_xor(v, 4, 64);
        v += __shfl_xor(v, 8, 64);
        sums[s] = v;
    }
    if (c == 0) {
#pragma unroll
        for (int m = 0; m < 4; ++m)
#pragma unroll
            for (int r = 0; r < 4; ++r)
                partial[(size_t)(rowbase + m * 16 + q * 4 + r) * 16 + split] = sums[m * 4 + r];
    }
}

// Kernel 3a: per-row lse - diag, block-reduced. One row per thread, 32 blocks.
__global__ __launch_bounds__(256) void row_lse_kernel(
    const float* __restrict__ partial, const float* __restrict__ diag,
    float* __restrict__ bsum, int n)
{
    __shared__ float red[256];
    const int row = blockIdx.x * 256 + threadIdx.x;
    float local = 0.0f;
    if (row < n) {
        const float4* p = (const float4*)(partial + (size_t)row * 16);
        float4 p0 = p[0], p1 = p[1], p2 = p[2], p3 = p[3];
        float s = (p0.x + p0.y + p0.z + p0.w) + (p1.x + p1.y + p1.z + p1.w)
                + (p2.x + p2.y + p2.z + p2.w) + (p3.x + p3.y + p3.z + p3.w);
        local = log2f(s) - diag[row];
    }
    red[threadIdx.x] = local;
    __syncthreads();
    for (int off = 128; off > 0; off >>= 1) {
        if (threadIdx.x < off) red[threadIdx.x] += red[threadIdx.x + off];
        __syncthreads();
    }
    if (threadIdx.x == 0) bsum[blockIdx.x] = red[0];
}

// Kernel 3b: final reduce of block sums -> loss.
__global__ __launch_bounds__(64) void final_kernel(
    const float* __restrict__ bsum, float* __restrict__ out, int nblocks, int n)
{
    float v = (threadIdx.x < nblocks) ? bsum[threadIdx.x] : 0.0f;
#pragma unroll
    for (int m = 1; m < 64; m <<= 1) v += __shfl_xor(v, m, 64);
    if (threadIdx.x == 0) out[0] = v * (LN2 / (float)n);
}

extern "C" void kernel_launch(void* const* d_in, const int* in_sizes, int n_in,
                              void* d_out, int out_size, void* d_ws, size_t ws_size,
                              hipStream_t stream) {
    const int n = in_sizes[0] / DIM;  // 8192
    const float* A = (const float*)d_in[0];
    const float* B = (const float*)d_in[1];
    float* out = (float*)d_out;

    // workspace layout
    unsigned short* Apk = (unsigned short*)d_ws;                 // n*DIM bf16 (packed granules)
    unsigned short* Bpk = Apk + (size_t)n * DIM;                 // n*DIM bf16 (packed granules)
    float* partial = (float*)(Bpk + (size_t)n * DIM);            // n*16 f32 (row-major)
    float* diag = partial + (size_t)n * 16;                      // n f32
    float* bsum = diag + n;                                      // 32 f32

    normpack_kernel<<<n / 16, 256, 0, stream>>>(A, B, Apk, Bpk, diag, n);

    // 32 rowblocks x 16 splits, XCD-decoded in-kernel
    gemm_lse_kernel<<<(n / 256) * 16, 256, 0, stream>>>(Apk, Bpk, partial, n);

    const int nred = (n + 255) / 256;  // 32
    row_lse_kernel<<<nred, 256, 0, stream>>>(partial, diag, bsum, n);
    final_kernel<<<1, 64, 0, stream>>>(bsum, out, nred, n);
}